// Round 6
// baseline (525.222 us; speedup 1.0000x reference)
//
#include <hip/hip_runtime.h>

// Problem constants (fixed by setup_inputs)
#define BATCH    4
#define NQ       10000
#define EMB      256
#define NH       8
#define DH       32
#define NL       4
#define NP       8
#define S_TOTAL  19560
#define NROW     (BATCH * NQ)          // 40000
#define VROWS    (BATCH * S_TOTAL)     // 78240

typedef _Float16 half8 __attribute__((ext_vector_type(8)));
typedef _Float16 half4v __attribute__((ext_vector_type(4)));
typedef _Float16 half2v __attribute__((ext_vector_type(2)));
typedef float floatx4 __attribute__((ext_vector_type(4)));

// ---------------------------------------------------------------------------
// W[256,N] f32 -> WT[N,256] f16
// ---------------------------------------------------------------------------
__global__ __launch_bounds__(256) void transp_f16(
    const float* __restrict__ W, _Float16* __restrict__ WT, int N) {
  const int tid = blockIdx.x * 256 + threadIdx.x;   // over N*256
  const int n = tid >> 8, k = tid & 255;
  WT[(size_t)n * 256 + k] = (_Float16)W[(size_t)k * N + n];
}

// fused bias [768] = concat(b_off[512], b_attn[256])
__global__ __launch_bounds__(256) void bias_cat(
    const float* __restrict__ b0, const float* __restrict__ b1,
    float* __restrict__ o) {
  const int t = blockIdx.x * 256 + threadIdx.x;
  if (t < 512) o[t] = b0[t];
  else if (t < 768) o[t] = b1[t - 512];
}

// ---------------------------------------------------------------------------
// MFMA GEMM, A-register-resident: C = A[M,256]_f32 @ WT[NC,256]^T + bias.
// K=256 is small enough that a wave's whole A slice (32 rows x 256 k f16)
// fits in 64 VGPRs. Each wave:
//   1. loads its 32 A rows from global as f32 ONCE, converts to f16 in-reg
//      (no conv pass, no LDS, no barriers),
//   2. loops n-chunks of 64 cols: B frags streamed from global (B is tiny,
//      L2-hot after the first block) with 1-deep prefetch, 2x4 grid of
//      16x16x32 MFMA tiles, immediate epilogue store per chunk.
// A is read from HBM exactly once per NYS (y-split for occupancy).
// Block = 4 waves x 32 rows = 128 rows. Wave tile 32 x 64.
//   A frag a[i][ks]: lane holds A[m0+16i+(lane&15)][32ks + quad*8 .. +7]
//   B frag:          lane holds WT[n0+16j+(lane&15)][32ks + quad*8 .. +7]
//   C/D: reg r -> C[16i + quad*4 + r][16j + (lane&15)]
// SWZ=true scatters C into [B, H, S, 32] layout for the sampler.
// ---------------------------------------------------------------------------
template <int NC, int NYS, bool SWZ>
__global__ __launch_bounds__(256, 2) void gemm3(
    const float* __restrict__ A, const _Float16* __restrict__ WT,
    const float* __restrict__ bias, _Float16* __restrict__ C, int M) {
  const int t = threadIdx.x;
  const int wave = t >> 6, lane = t & 63;
  const int l15 = lane & 15, quad = lane >> 4;
  const int m0 = blockIdx.x * 128 + wave * 32;
  const int nlo = blockIdx.y * (NC / NYS);
  const int nhi = nlo + (NC / NYS);

  const float* Arow[2];
  #pragma unroll
  for (int i = 0; i < 2; ++i)
    Arow[i] = A + (size_t)min(m0 + 16 * i + l15, M - 1) * 256 + quad * 8;

  // ---- load + convert the wave's whole A slice into registers ----
  half8 a[2][8];
  #pragma unroll
  for (int i = 0; i < 2; ++i) {
    float4 tmp[8][2];
    #pragma unroll
    for (int ks = 0; ks < 8; ++ks) {
      tmp[ks][0] = *(const float4*)(Arow[i] + ks * 32);
      tmp[ks][1] = *(const float4*)(Arow[i] + ks * 32 + 4);
    }
    #pragma unroll
    for (int ks = 0; ks < 8; ++ks) {
      a[i][ks][0] = (_Float16)tmp[ks][0].x; a[i][ks][1] = (_Float16)tmp[ks][0].y;
      a[i][ks][2] = (_Float16)tmp[ks][0].z; a[i][ks][3] = (_Float16)tmp[ks][0].w;
      a[i][ks][4] = (_Float16)tmp[ks][1].x; a[i][ks][5] = (_Float16)tmp[ks][1].y;
      a[i][ks][6] = (_Float16)tmp[ks][1].z; a[i][ks][7] = (_Float16)tmp[ks][1].w;
    }
  }

  const _Float16* Bb = WT + (size_t)l15 * 256 + quad * 8;

  for (int n0 = nlo; n0 < nhi; n0 += 64) {
    float bc[4];
    #pragma unroll
    for (int j = 0; j < 4; ++j) bc[j] = bias[n0 + 16 * j + l15];

    floatx4 acc[2][4] = {};
    half8 bcur[4], bnxt[4];
    #pragma unroll
    for (int j = 0; j < 4; ++j)
      bcur[j] = *(const half8*)(Bb + (size_t)(n0 + 16 * j) * 256);

    #pragma unroll
    for (int ks = 0; ks < 8; ++ks) {
      if (ks < 7) {
        #pragma unroll
        for (int j = 0; j < 4; ++j)
          bnxt[j] = *(const half8*)(Bb + (size_t)(n0 + 16 * j) * 256 + (ks + 1) * 32);
      }
      #pragma unroll
      for (int j = 0; j < 4; ++j)
        #pragma unroll
        for (int i = 0; i < 2; ++i)
          acc[i][j] = __builtin_amdgcn_mfma_f32_16x16x32_f16(a[i][ks], bcur[j], acc[i][j], 0, 0, 0);
      #pragma unroll
      for (int j = 0; j < 4; ++j) bcur[j] = bnxt[j];
    }

    #pragma unroll
    for (int i = 0; i < 2; ++i) {
      #pragma unroll
      for (int r = 0; r < 4; ++r) {
        const int row = m0 + 16 * i + quad * 4 + r;
        if (row < M) {
          if (SWZ) {
            const int b = row / S_TOTAL;
            const int s = row - b * S_TOTAL;
            #pragma unroll
            for (int j = 0; j < 4; ++j) {
              const int col = n0 + 16 * j + l15;
              const size_t dst =
                  (((size_t)b * NH + (col >> 5)) * S_TOTAL + s) * 32 + (col & 31);
              C[dst] = (_Float16)(acc[i][j][r] + bc[j]);
            }
          } else {
            #pragma unroll
            for (int j = 0; j < 4; ++j)
              C[(size_t)row * NC + n0 + 16 * j + l15] =
                  (_Float16)(acc[i][j][r] + bc[j]);
          }
        }
      }
    }
  }
}

// ---------------------------------------------------------------------------
// Fused softmax + deformable bilinear sampling. vproj layout [B,H,S,32]:
// the (y,x0)/(y,x1) corner pair is 128 B contiguous -> 2 segments per point.
// Grid remap: blk = b + 4*qidx so XCD k (round-robin blk%8) sees only
// batch k&3 -> per-XCD v working set 10 MB instead of 40.
// Phase 1: thread t=(h,l,p) -> softmax (xor-shuffles), then for each of 2
// row-pairs: clamped base addr + left/right corner weights into LDS.
// Phase 2: 32-lane head group, lane = (ph, side, chquad): per point-half,
// 2 half4 loads (top/bottom rowpair), 4 fma each; unroll 8 -> 16 loads in
// flight per lane. Reduce over side (xor 8) and ph (xor 16).
// ---------------------------------------------------------------------------
__global__ __launch_bounds__(256) void msda_sample(
    const _Float16* __restrict__ vproj,     // [B,H,S,32] f16 (+guards)
    const _Float16* __restrict__ fused,     // [B*Q, 768] f16: off(512)|logit(256)
    const float* __restrict__ ref,          // [B*Q, 4, 2] f32
    float* __restrict__ out) {              // [B*Q, 256] f32
  const int lvl_h[NL] = {92, 46, 23, 12};
  const int lvl_w[NL] = {160, 80, 40, 20};
  const int lvl_s[NL] = {0, 14720, 18400, 19320};

  __shared__ int   addr_s[512];   // [(h*32+p)*2 + rp]
  __shared__ float wl_s[512];
  __shared__ float wr_s[512];

  const int t   = threadIdx.x;
  const int blk = blockIdx.x;
  const int b   = blk & 3;             // pins batch to XCD (blk%8 round-robin)
  const int q   = blk >> 2;
  const int row = b * NQ + q;

  const int h  = t >> 5;
  const int lp = t & 31;
  const int l  = lp >> 3;
  const int p  = lp & 7;

  // ---- softmax over the 32 (l,p) logits of this head (xor shuffles) ----
  const float logit = (float)fused[(size_t)row * 768 + 512 + t];
  float mxv = logit;
  #pragma unroll
  for (int m = 1; m < 32; m <<= 1) mxv = fmaxf(mxv, __shfl_xor(mxv, m));
  const float e = __expf(logit - mxv);
  float sum = e;
  #pragma unroll
  for (int m = 1; m < 32; m <<= 1) sum += __shfl_xor(sum, m);
  const float attnw = e / sum;

  // ---- location & bilinear setup ----
  const half2v o2 = *(const half2v*)(fused + (size_t)row * 768 + 2 * t);
  const float ox = (float)o2[0], oy = (float)o2[1];
  const int z = p & 3;                       // NP=8 split (2,4): z = p % 4
  const float rx = ref[((size_t)row * 4 + z) * 2 + 0];
  const float ry = ref[((size_t)row * 4 + z) * 2 + 1];
  const int Wl = lvl_w[l], Hl = lvl_h[l], st = lvl_s[l];

  const float px = fmaf(rx, (float)Wl, ox) - 0.5f;
  const float py = fmaf(ry, (float)Hl, oy) - 0.5f;
  const float x0f = floorf(px), y0f = floorf(py);
  const float wx = px - x0f, wy = py - y0f;
  const int x0 = (int)x0f, y0 = (int)y0f;
  const int x1 = x0 + 1,   y1 = y0 + 1;

  // x: one 128B segment based at xb covers slots xb (left) and xb+1 (right)
  const float mx0 = (x0 >= 0 && x0 < Wl) ? 1.f : 0.f;
  const float mx1 = (x1 >= 0 && x1 < Wl) ? 1.f : 0.f;
  const float my0 = (y0 >= 0 && y0 < Hl) ? 1.f : 0.f;
  const float my1 = (y1 >= 0 && y1 < Hl) ? 1.f : 0.f;
  const int xb  = min(max(x0, -1), Wl - 1);          // guard pages cover x=-1/W
  const int cy0 = min(max(y0, 0), Hl - 1);
  const int cy1 = min(max(y1, 0), Hl - 1);

  const int bh   = b * NH + h;
  const int lbase = bh * S_TOTAL + st;
  const float wlc = attnw * (1.f - wx) * mx0;
  const float wrc = attnw * wx * mx1;

  addr_s[2 * t + 0] = (lbase + cy0 * Wl + xb) * 32;
  addr_s[2 * t + 1] = (lbase + cy1 * Wl + xb) * 32;
  wl_s[2 * t + 0] = wlc * (1.f - wy) * my0;
  wr_s[2 * t + 0] = wrc * (1.f - wy) * my0;
  wl_s[2 * t + 1] = wlc * wy * my1;
  wr_s[2 * t + 1] = wrc * wy * my1;
  __syncthreads();

  // ---- phase 2: lane g = (ph, side, chquad) within head group ----
  const int g  = t & 31;
  const int c  = g & 7;           // channel quad: channels 4c..4c+3
  const int sd = (g >> 3) & 1;    // 0 = left corner, 1 = right corner
  const int ph = g >> 4;          // point parity
  const int ldoff = sd * 32 + 4 * c;

  float a0 = 0.f, a1 = 0.f, a2 = 0.f, a3 = 0.f;
  #pragma unroll 8
  for (int i = 0; i < 16; ++i) {
    const int idx = ((h << 5) + 2 * i + ph) * 2;
    const int at = addr_s[idx],     ab = addr_s[idx + 1];
    const float wt = sd ? wr_s[idx]     : wl_s[idx];
    const float wb = sd ? wr_s[idx + 1] : wl_s[idx + 1];
    const half4v vt = *(const half4v*)(vproj + at + ldoff);
    const half4v vb = *(const half4v*)(vproj + ab + ldoff);
    a0 = fmaf(wt, (float)vt[0], a0); a1 = fmaf(wt, (float)vt[1], a1);
    a2 = fmaf(wt, (float)vt[2], a2); a3 = fmaf(wt, (float)vt[3], a3);
    a0 = fmaf(wb, (float)vb[0], a0); a1 = fmaf(wb, (float)vb[1], a1);
    a2 = fmaf(wb, (float)vb[2], a2); a3 = fmaf(wb, (float)vb[3], a3);
  }

  // reduce over side (xor 8) and point parity (xor 16)
  a0 += __shfl_xor(a0, 8);  a1 += __shfl_xor(a1, 8);
  a2 += __shfl_xor(a2, 8);  a3 += __shfl_xor(a3, 8);
  a0 += __shfl_xor(a0, 16); a1 += __shfl_xor(a1, 16);
  a2 += __shfl_xor(a2, 16); a3 += __shfl_xor(a3, 16);

  if (g < 8) {    // sd==0 && ph==0: 8 lanes own the 8 channel quads
    float4 o; o.x = a0; o.y = a1; o.z = a2; o.w = a3;
    *(float4*)(out + (size_t)row * 256 + (h << 5) + 4 * c) = o;
  }
}

extern "C" void kernel_launch(void* const* d_in, const int* in_sizes, int n_in,
                              void* d_out, int out_size, void* d_ws, size_t ws_size,
                              hipStream_t stream) {
  const float* query  = (const float*)d_in[0];  // [4,10000,256]
  const float* value  = (const float*)d_in[1];  // [4,19560,256]
  const float* refpts = (const float*)d_in[2];  // [4,10000,4,2]
  const float* w_off  = (const float*)d_in[3];  // [256,512]
  const float* b_off  = (const float*)d_in[4];  // [512]
  const float* w_attn = (const float*)d_in[5];  // [256,256]
  const float* b_attn = (const float*)d_in[6];  // [256]
  const float* w_val  = (const float*)d_in[7];  // [256,256]
  const float* b_val  = (const float*)d_in[8];  // [256]
  float* out = (float*)d_out;

  // workspace layout (16B-multiple segments; 256B guards around vh for the
  // x=-1 / x=W edge reads, whose weights are zero)
  char* p = (char*)d_ws;
  p += 256;                                                         // front guard
  _Float16* vh    = (_Float16*)p;  p += (size_t)VROWS * 256 * 2;    // 40.1 MB
  p += 256;                                                         // back guard
  _Float16* wT768 = (_Float16*)p;  p += (size_t)768 * 256 * 2;
  _Float16* wvaT  = (_Float16*)p;  p += (size_t)256 * 256 * 2;
  float*    bias768 = (float*)p;   p += 768 * 4;
  _Float16* fused_h = (_Float16*)p; p += (size_t)NROW * 768 * 2;    // 61.4 MB

  // prep: weight transposes (f32->f16), fused bias
  transp_f16<<<512, 256, 0, stream>>>(w_off, wT768, 512);
  transp_f16<<<256, 256, 0, stream>>>(w_attn, wT768 + 512 * 256, 256);
  transp_f16<<<256, 256, 0, stream>>>(w_val, wvaT, 256);
  bias_cat<<<3, 256, 0, stream>>>(b_off, b_attn, bias768);

  // GEMMs, A-register-resident, f32 A read directly:
  // v = value@w_val -> [B,H,S,32] swizzled; fused = query@[w_off|w_attn]
  gemm3<256, 1, true><<<dim3((VROWS + 127) / 128, 1), 256, 0, stream>>>(
      value, wvaT, b_val, vh, VROWS);
  gemm3<768, 2, false><<<dim3((NROW + 127) / 128, 2), 256, 0, stream>>>(
      query, wT768, bias768, fused_h, NROW);

  // softmax + sample + weighted sum
  msda_sample<<<dim3(NROW), 256, 0, stream>>>(vh, fused_h, refpts, out);
}

// Round 8
// 482.113 us; speedup vs baseline: 1.0894x; 1.0894x over previous
//
#include <hip/hip_runtime.h>

// Problem constants (fixed by setup_inputs)
#define BATCH    4
#define NQ       10000
#define EMB      256
#define NH       8
#define DH       32
#define NL       4
#define NP       8
#define S_TOTAL  19560
#define NROW     (BATCH * NQ)          // 40000
#define VROWS    (BATCH * S_TOTAL)     // 78240

typedef _Float16 half8 __attribute__((ext_vector_type(8)));
typedef _Float16 half4v __attribute__((ext_vector_type(4)));
typedef _Float16 half2v __attribute__((ext_vector_type(2)));
typedef float floatx4 __attribute__((ext_vector_type(4)));

// ---------------------------------------------------------------------------
// W[256,N] f32 -> WTs[N,256] f16 with XOR-swizzled 16B chunks:
// logical (n, k) with k = c*8+e (c=0..31 16B-chunks, e=0..7) lands at
// WTs[n*256 + ((c ^ (n&7))<<3) + e]. The GEMM stages rows of WTs linearly
// into LDS, and the swizzle makes the ds_read_b128 fragment reads hit all
// 32 banks evenly (<=2-way aliasing, free).
// ---------------------------------------------------------------------------
__global__ __launch_bounds__(256) void transp_swz(
    const float* __restrict__ W, _Float16* __restrict__ WTs, int N) {
  const int tid = blockIdx.x * 256 + threadIdx.x;   // over N*256
  const int n = tid >> 8, k = tid & 255;
  const int c = k >> 3, e = k & 7;
  WTs[(size_t)n * 256 + (((c ^ (n & 7)) << 3) + e)] = (_Float16)W[(size_t)k * N + n];
}

// fused bias [768] = concat(b_off[512], b_attn[256])
__global__ __launch_bounds__(256) void bias_cat(
    const float* __restrict__ b0, const float* __restrict__ b1,
    float* __restrict__ o) {
  const int t = blockIdx.x * 256 + threadIdx.x;
  if (t < 512) o[t] = b0[t];
  else if (t < 768) o[t] = b1[t - 512];
}

// ---------------------------------------------------------------------------
// MFMA GEMM: A-register-resident + B-chunk-in-LDS.
//   C = A[M,256]_f32 @ WTs[NC,256]^T + bias
// Block: 256 thr = 4 waves x 64 rows = 256 rows. Each wave:
//   1. loads its 64 A rows (f32, from HBM, ONCE) -> converts to f16 in-reg
//      (a[4][8] = 128 VGPR). No conv pass, A never re-read (x NYS).
//   2. loops n-chunks of 64 cols: block stages the B chunk (64x256 f16 =
//      32 KB = 2048 half8 = 8 half8 per thread, swizzled) into LDS, then
//      8 k-steps x 16 MFMA with B from LDS - no global deps in the k-loop.
// SWZ=true scatters C into [B, H, S, 32] layout for the sampler.
// ---------------------------------------------------------------------------
template <int NC, int NYS, bool SWZ>
__global__ __launch_bounds__(256, 2) void gemm4(
    const float* __restrict__ A, const _Float16* __restrict__ WTs,
    const float* __restrict__ bias, _Float16* __restrict__ C, int M) {
  __shared__ _Float16 bsm[64 * 256];   // 32 KB B chunk (swizzled rows)
  const int t = threadIdx.x;
  const int wave = t >> 6, lane = t & 63;
  const int l15 = lane & 15, quad = lane >> 4;
  const int m0 = blockIdx.x * 256 + wave * 64;
  const int nlo = blockIdx.y * (NC / NYS);
  const int nchunks = (NC / NYS) / 64;

  // ---- load + convert the wave's whole A slice (64 rows x 256) ----
  half8 a[4][8];
  #pragma unroll
  for (int i = 0; i < 4; ++i) {
    const float* Ar = A + (size_t)min(m0 + 16 * i + l15, M - 1) * 256 + quad * 8;
    #pragma unroll
    for (int ks = 0; ks < 8; ++ks) {
      const float4 f0 = *(const float4*)(Ar + ks * 32);
      const float4 f1 = *(const float4*)(Ar + ks * 32 + 4);
      a[i][ks][0] = (_Float16)f0.x; a[i][ks][1] = (_Float16)f0.y;
      a[i][ks][2] = (_Float16)f0.z; a[i][ks][3] = (_Float16)f0.w;
      a[i][ks][4] = (_Float16)f1.x; a[i][ks][5] = (_Float16)f1.y;
      a[i][ks][6] = (_Float16)f1.z; a[i][ks][7] = (_Float16)f1.w;
    }
  }

  const _Float16* src = WTs + (size_t)nlo * 256;

  for (int ch = 0; ch < nchunks; ++ch) {
    // ---- stage B chunk: 64x256 f16 = 2048 half8; 8 half8 per thread ----
    __syncthreads();
    #pragma unroll
    for (int i = 0; i < 8; ++i)
      *(half8*)&bsm[t * 8 + i * 2048] = *(const half8*)(src + t * 8 + i * 2048);
    __syncthreads();

    floatx4 acc[4][4] = {};
    #pragma unroll
    for (int ks = 0; ks < 8; ++ks) {
      half8 b[4];
      #pragma unroll
      for (int j = 0; j < 4; ++j)
        b[j] = *(const half8*)&bsm[(16 * j + l15) * 256 +
                                   ((((ks * 4 + quad) ^ (l15 & 7))) << 3)];
      #pragma unroll
      for (int j = 0; j < 4; ++j)
        #pragma unroll
        for (int i = 0; i < 4; ++i)
          acc[i][j] = __builtin_amdgcn_mfma_f32_16x16x32_f16(a[i][ks], b[j], acc[i][j], 0, 0, 0);
    }

    const int nc0 = nlo + ch * 64;
    float bc[4];
    #pragma unroll
    for (int j = 0; j < 4; ++j) bc[j] = bias[nc0 + 16 * j + l15];

    #pragma unroll
    for (int i = 0; i < 4; ++i) {
      #pragma unroll
      for (int r = 0; r < 4; ++r) {
        const int row = m0 + 16 * i + quad * 4 + r;
        if (row < M) {
          if (SWZ) {
            const int b = row / S_TOTAL;
            const int s = row - b * S_TOTAL;
            #pragma unroll
            for (int j = 0; j < 4; ++j) {
              const int col = nc0 + 16 * j + l15;
              const size_t dst =
                  (((size_t)b * NH + (col >> 5)) * S_TOTAL + s) * 32 + (col & 31);
              C[dst] = (_Float16)(acc[i][j][r] + bc[j]);
            }
          } else {
            #pragma unroll
            for (int j = 0; j < 4; ++j)
              C[(size_t)row * NC + nc0 + 16 * j + l15] =
                  (_Float16)(acc[i][j][r] + bc[j]);
          }
        }
      }
    }
    src += 64 * 256;
  }
}

// ---------------------------------------------------------------------------
// Fused softmax + deformable bilinear sampling (unchanged from round 5).
// vproj layout [B,H,S,32]; XCD-pinned batches; rowpair 2-segment gathers.
// ---------------------------------------------------------------------------
__global__ __launch_bounds__(256) void msda_sample(
    const _Float16* __restrict__ vproj,     // [B,H,S,32] f16 (+guards)
    const _Float16* __restrict__ fused,     // [B*Q, 768] f16: off(512)|logit(256)
    const float* __restrict__ ref,          // [B*Q, 4, 2] f32
    float* __restrict__ out) {              // [B*Q, 256] f32
  const int lvl_h[NL] = {92, 46, 23, 12};
  const int lvl_w[NL] = {160, 80, 40, 20};
  const int lvl_s[NL] = {0, 14720, 18400, 19320};

  __shared__ int   addr_s[512];   // [(h*32+p)*2 + rp]
  __shared__ float wl_s[512];
  __shared__ float wr_s[512];

  const int t   = threadIdx.x;
  const int blk = blockIdx.x;
  const int b   = blk & 3;             // pins batch to XCD (blk%8 round-robin)
  const int q   = blk >> 2;
  const int row = b * NQ + q;

  const int h  = t >> 5;
  const int lp = t & 31;
  const int l  = lp >> 3;
  const int p  = lp & 7;

  // ---- softmax over the 32 (l,p) logits of this head (xor shuffles) ----
  const float logit = (float)fused[(size_t)row * 768 + 512 + t];
  float mxv = logit;
  #pragma unroll
  for (int m = 1; m < 32; m <<= 1) mxv = fmaxf(mxv, __shfl_xor(mxv, m));
  const float e = __expf(logit - mxv);
  float sum = e;
  #pragma unroll
  for (int m = 1; m < 32; m <<= 1) sum += __shfl_xor(sum, m);
  const float attnw = e / sum;

  // ---- location & bilinear setup ----
  const half2v o2 = *(const half2v*)(fused + (size_t)row * 768 + 2 * t);
  const float ox = (float)o2[0], oy = (float)o2[1];
  const int z = p & 3;                       // NP=8 split (2,4): z = p % 4
  const float rx = ref[((size_t)row * 4 + z) * 2 + 0];
  const float ry = ref[((size_t)row * 4 + z) * 2 + 1];
  const int Wl = lvl_w[l], Hl = lvl_h[l], st = lvl_s[l];

  const float px = fmaf(rx, (float)Wl, ox) - 0.5f;
  const float py = fmaf(ry, (float)Hl, oy) - 0.5f;
  const float x0f = floorf(px), y0f = floorf(py);
  const float wx = px - x0f, wy = py - y0f;
  const int x0 = (int)x0f, y0 = (int)y0f;
  const int x1 = x0 + 1,   y1 = y0 + 1;

  // x: one 128B segment based at xb covers slots xb (left) and xb+1 (right)
  const float mx0 = (x0 >= 0 && x0 < Wl) ? 1.f : 0.f;
  const float mx1 = (x1 >= 0 && x1 < Wl) ? 1.f : 0.f;
  const float my0 = (y0 >= 0 && y0 < Hl) ? 1.f : 0.f;
  const float my1 = (y1 >= 0 && y1 < Hl) ? 1.f : 0.f;
  const int xb  = min(max(x0, -1), Wl - 1);          // guard pages cover x=-1/W
  const int cy0 = min(max(y0, 0), Hl - 1);
  const int cy1 = min(max(y1, 0), Hl - 1);

  const int bh   = b * NH + h;
  const int lbase = bh * S_TOTAL + st;
  const float wlc = attnw * (1.f - wx) * mx0;
  const float wrc = attnw * wx * mx1;

  addr_s[2 * t + 0] = (lbase + cy0 * Wl + xb) * 32;
  addr_s[2 * t + 1] = (lbase + cy1 * Wl + xb) * 32;
  wl_s[2 * t + 0] = wlc * (1.f - wy) * my0;
  wr_s[2 * t + 0] = wrc * (1.f - wy) * my0;
  wl_s[2 * t + 1] = wlc * wy * my1;
  wr_s[2 * t + 1] = wrc * wy * my1;
  __syncthreads();

  // ---- phase 2: lane g = (ph, side, chquad) within head group ----
  const int g  = t & 31;
  const int c  = g & 7;           // channel quad: channels 4c..4c+3
  const int sd = (g >> 3) & 1;    // 0 = left corner, 1 = right corner
  const int ph = g >> 4;          // point parity
  const int ldoff = sd * 32 + 4 * c;

  float a0 = 0.f, a1 = 0.f, a2 = 0.f, a3 = 0.f;
  #pragma unroll 8
  for (int i = 0; i < 16; ++i) {
    const int idx = ((h << 5) + 2 * i + ph) * 2;
    const int at = addr_s[idx],     ab = addr_s[idx + 1];
    const float wt = sd ? wr_s[idx]     : wl_s[idx];
    const float wb = sd ? wr_s[idx + 1] : wl_s[idx + 1];
    const half4v vt = *(const half4v*)(vproj + at + ldoff);
    const half4v vb = *(const half4v*)(vproj + ab + ldoff);
    a0 = fmaf(wt, (float)vt[0], a0); a1 = fmaf(wt, (float)vt[1], a1);
    a2 = fmaf(wt, (float)vt[2], a2); a3 = fmaf(wt, (float)vt[3], a3);
    a0 = fmaf(wb, (float)vb[0], a0); a1 = fmaf(wb, (float)vb[1], a1);
    a2 = fmaf(wb, (float)vb[2], a2); a3 = fmaf(wb, (float)vb[3], a3);
  }

  // reduce over side (xor 8) and point parity (xor 16)
  a0 += __shfl_xor(a0, 8);  a1 += __shfl_xor(a1, 8);
  a2 += __shfl_xor(a2, 8);  a3 += __shfl_xor(a3, 8);
  a0 += __shfl_xor(a0, 16); a1 += __shfl_xor(a1, 16);
  a2 += __shfl_xor(a2, 16); a3 += __shfl_xor(a3, 16);

  if (g < 8) {    // sd==0 && ph==0: 8 lanes own the 8 channel quads
    float4 o; o.x = a0; o.y = a1; o.z = a2; o.w = a3;
    *(float4*)(out + (size_t)row * 256 + (h << 5) + 4 * c) = o;
  }
}

extern "C" void kernel_launch(void* const* d_in, const int* in_sizes, int n_in,
                              void* d_out, int out_size, void* d_ws, size_t ws_size,
                              hipStream_t stream) {
  const float* query  = (const float*)d_in[0];  // [4,10000,256]
  const float* value  = (const float*)d_in[1];  // [4,19560,256]
  const float* refpts = (const float*)d_in[2];  // [4,10000,4,2]
  const float* w_off  = (const float*)d_in[3];  // [256,512]
  const float* b_off  = (const float*)d_in[4];  // [512]
  const float* w_attn = (const float*)d_in[5];  // [256,256]
  const float* b_attn = (const float*)d_in[6];  // [256]
  const float* w_val  = (const float*)d_in[7];  // [256,256]
  const float* b_val  = (const float*)d_in[8];  // [256]
  float* out = (float*)d_out;

  // workspace layout (16B-multiple segments; 256B guards around vh for the
  // x=-1 / x=W edge reads, whose weights are zero)
  char* p = (char*)d_ws;
  p += 256;                                                         // front guard
  _Float16* vh    = (_Float16*)p;  p += (size_t)VROWS * 256 * 2;    // 40.1 MB
  p += 256;                                                         // back guard
  _Float16* wT768 = (_Float16*)p;  p += (size_t)768 * 256 * 2;      // swizzled
  _Float16* wvaT  = (_Float16*)p;  p += (size_t)256 * 256 * 2;      // swizzled
  float*    bias768 = (float*)p;   p += 768 * 4;
  _Float16* fused_h = (_Float16*)p; p += (size_t)NROW * 768 * 2;    // 61.4 MB

  // prep: swizzled weight transposes (f32->f16), fused bias
  transp_swz<<<512, 256, 0, stream>>>(w_off, wT768, 512);
  transp_swz<<<256, 256, 0, stream>>>(w_attn, wT768 + 512 * 256, 256);
  transp_swz<<<256, 256, 0, stream>>>(w_val, wvaT, 256);
  bias_cat<<<3, 256, 0, stream>>>(b_off, b_attn, bias768);

  // GEMMs: A register-resident, B chunks via LDS.
  // v = value@w_val -> [B,H,S,32] swizzled; fused = query@[w_off|w_attn]
  gemm4<256, 1, true><<<dim3((VROWS + 255) / 256, 1), 256, 0, stream>>>(
      value, wvaT, b_val, vh, VROWS);
  gemm4<768, 2, false><<<dim3((NROW + 255) / 256, 2), 256, 0, stream>>>(
      query, wT768, bias768, fused_h, NROW);

  // softmax + sample + weighted sum
  msda_sample<<<dim3(NROW), 256, 0, stream>>>(vh, fused_h, refpts, out);
}

// Round 9
// 402.764 us; speedup vs baseline: 1.3040x; 1.1970x over previous
//
#include <hip/hip_runtime.h>

// Problem constants (fixed by setup_inputs)
#define BATCH    4
#define NQ       10000
#define EMB      256
#define NH       8
#define DH       32
#define NL       4
#define NP       8
#define S_TOTAL  19560
#define NROW     (BATCH * NQ)          // 40000
#define VROWS    (BATCH * S_TOTAL)     // 78240

typedef _Float16 half8 __attribute__((ext_vector_type(8)));
typedef _Float16 half4v __attribute__((ext_vector_type(4)));
typedef _Float16 half2v __attribute__((ext_vector_type(2)));
typedef float floatx4 __attribute__((ext_vector_type(4)));

// ---------------------------------------------------------------------------
// One-shot weight prep: transpose+swizzle all three weight matrices to f16.
// Logical row n (0..1279): [0,512) w_off -> wT768, [512,768) w_attn -> wT768,
// [768,1280) ... w_val (256 rows) -> wvaT. Swizzle: 16B chunk c of row n
// lands at chunk c ^ (n&7) (row-local n; offsets are multiples of 8 so &7 is
// preserved).
// ---------------------------------------------------------------------------
__global__ __launch_bounds__(256) void prep_weights(
    const float* __restrict__ w_off, const float* __restrict__ w_attn,
    const float* __restrict__ w_val, _Float16* __restrict__ wT768,
    _Float16* __restrict__ wvaT) {
  const int tid = blockIdx.x * 256 + threadIdx.x;   // over 1024*256
  const int n = tid >> 8, k = tid & 255;
  const int c = k >> 3, e = k & 7;
  const int swz = ((c ^ (n & 7)) << 3) + e;
  float v;
  _Float16* dst;
  if (n < 512)      { v = w_off[(size_t)k * 512 + n];          dst = wT768 + (size_t)n * 256; }
  else if (n < 768) { v = w_attn[(size_t)k * 256 + (n - 512)]; dst = wT768 + (size_t)n * 256; }
  else              { v = w_val[(size_t)k * 256 + (n - 768)];  dst = wvaT + (size_t)(n - 768) * 256; }
  dst[swz] = (_Float16)v;
}

// ---------------------------------------------------------------------------
// MFMA GEMM: A-register-resident + B-chunk-in-LDS, 3 blocks/CU.
//   C = A[M,256]_f32 @ WTs[NC,256]^T + bias(col-select)
// Block: 256 thr = 4 waves x 32 rows = 128 rows. Each wave:
//   1. loads its 32 A rows (f32, HBM, ONCE) -> f16 in-reg (a[2][8], 64 VGPR)
//   2. per 64-col chunk: block stages B (64x256 f16 = 32 KB, swizzled) into
//      LDS (8 half8/thread), then 8 k-steps x 8 MFMA, no global deps.
// Bias: col < SPLITC ? bias0[col] : bias1[col-SPLITC].
// SWZ=true scatters C into [B, H, S, 32] layout for the sampler.
// ---------------------------------------------------------------------------
template <int NC, int NYS, bool SWZ>
__global__ __launch_bounds__(256, 3) void gemm5(
    const float* __restrict__ A, const _Float16* __restrict__ WTs,
    const float* __restrict__ bias0, const float* __restrict__ bias1,
    int splitc, _Float16* __restrict__ C, int M) {
  __shared__ _Float16 bsm[64 * 256];   // 32 KB B chunk (swizzled rows)
  const int t = threadIdx.x;
  const int wave = t >> 6, lane = t & 63;
  const int l15 = lane & 15, quad = lane >> 4;
  const int m0 = blockIdx.x * 128 + wave * 32;
  const int nlo = blockIdx.y * (NC / NYS);
  const int nchunks = (NC / NYS) / 64;

  // ---- load + convert the wave's A slice (32 rows x 256) ----
  half8 a[2][8];
  #pragma unroll
  for (int i = 0; i < 2; ++i) {
    const float* Ar = A + (size_t)min(m0 + 16 * i + l15, M - 1) * 256 + quad * 8;
    #pragma unroll
    for (int ks = 0; ks < 8; ++ks) {
      const float4 f0 = *(const float4*)(Ar + ks * 32);
      const float4 f1 = *(const float4*)(Ar + ks * 32 + 4);
      a[i][ks][0] = (_Float16)f0.x; a[i][ks][1] = (_Float16)f0.y;
      a[i][ks][2] = (_Float16)f0.z; a[i][ks][3] = (_Float16)f0.w;
      a[i][ks][4] = (_Float16)f1.x; a[i][ks][5] = (_Float16)f1.y;
      a[i][ks][6] = (_Float16)f1.z; a[i][ks][7] = (_Float16)f1.w;
    }
  }

  const _Float16* src = WTs + (size_t)nlo * 256;

  for (int ch = 0; ch < nchunks; ++ch) {
    // ---- stage B chunk: 64x256 f16 = 2048 half8; 8 half8 per thread ----
    __syncthreads();
    #pragma unroll
    for (int i = 0; i < 8; ++i)
      *(half8*)&bsm[t * 8 + i * 2048] = *(const half8*)(src + t * 8 + i * 2048);
    __syncthreads();

    floatx4 acc[2][4] = {};
    #pragma unroll
    for (int ks = 0; ks < 8; ++ks) {
      half8 b[4];
      #pragma unroll
      for (int j = 0; j < 4; ++j)
        b[j] = *(const half8*)&bsm[(16 * j + l15) * 256 +
                                   ((((ks * 4 + quad) ^ (l15 & 7))) << 3)];
      #pragma unroll
      for (int j = 0; j < 4; ++j)
        #pragma unroll
        for (int i = 0; i < 2; ++i)
          acc[i][j] = __builtin_amdgcn_mfma_f32_16x16x32_f16(a[i][ks], b[j], acc[i][j], 0, 0, 0);
    }

    const int nc0 = nlo + ch * 64;
    float bc[4];
    #pragma unroll
    for (int j = 0; j < 4; ++j) {
      const int col = nc0 + 16 * j + l15;
      bc[j] = (col < splitc) ? bias0[col] : bias1[col - splitc];
    }

    #pragma unroll
    for (int i = 0; i < 2; ++i) {
      #pragma unroll
      for (int r = 0; r < 4; ++r) {
        const int row = m0 + 16 * i + quad * 4 + r;
        if (row < M) {
          if (SWZ) {
            const int b = row / S_TOTAL;
            const int s = row - b * S_TOTAL;
            #pragma unroll
            for (int j = 0; j < 4; ++j) {
              const int col = nc0 + 16 * j + l15;
              const size_t dst =
                  (((size_t)b * NH + (col >> 5)) * S_TOTAL + s) * 32 + (col & 31);
              C[dst] = (_Float16)(acc[i][j][r] + bc[j]);
            }
          } else {
            #pragma unroll
            for (int j = 0; j < 4; ++j)
              C[(size_t)row * NC + nc0 + 16 * j + l15] =
                  (_Float16)(acc[i][j][r] + bc[j]);
          }
        }
      }
    }
    src += 64 * 256;
  }
}

// ---------------------------------------------------------------------------
// Fused softmax + deformable bilinear sampling. vproj [B,H,S,32];
// XCD-pinned batches; rowpair 2-segment gathers.
// Phase 2 restructured load-all-then-fma: 32 half4 loads into register
// arrays (forces high memory-level parallelism; round-8 counters showed
// VGPR_Count=20 -> compiler had serialized the gathers), then 256 fmas.
// __launch_bounds__(256,4) licenses ~128 VGPR.
// ---------------------------------------------------------------------------
__global__ __launch_bounds__(256, 4) void msda_sample(
    const _Float16* __restrict__ vproj,     // [B,H,S,32] f16 (+guards)
    const _Float16* __restrict__ fused,     // [B*Q, 768] f16: off(512)|logit(256)
    const float* __restrict__ ref,          // [B*Q, 4, 2] f32
    float* __restrict__ out) {              // [B*Q, 256] f32
  const int lvl_h[NL] = {92, 46, 23, 12};
  const int lvl_w[NL] = {160, 80, 40, 20};
  const int lvl_s[NL] = {0, 14720, 18400, 19320};

  __shared__ int   addr_s[512];   // [(h*32+p)*2 + rp]
  __shared__ float wl_s[512];
  __shared__ float wr_s[512];

  const int t   = threadIdx.x;
  const int blk = blockIdx.x;
  const int b   = blk & 3;             // pins batch to XCD (blk%8 round-robin)
  const int q   = blk >> 2;
  const int row = b * NQ + q;

  const int h  = t >> 5;
  const int lp = t & 31;
  const int l  = lp >> 3;
  const int p  = lp & 7;

  // ---- softmax over the 32 (l,p) logits of this head (xor shuffles) ----
  const float logit = (float)fused[(size_t)row * 768 + 512 + t];
  float mxv = logit;
  #pragma unroll
  for (int m = 1; m < 32; m <<= 1) mxv = fmaxf(mxv, __shfl_xor(mxv, m));
  const float e = __expf(logit - mxv);
  float sum = e;
  #pragma unroll
  for (int m = 1; m < 32; m <<= 1) sum += __shfl_xor(sum, m);
  const float attnw = e / sum;

  // ---- location & bilinear setup ----
  const half2v o2 = *(const half2v*)(fused + (size_t)row * 768 + 2 * t);
  const float ox = (float)o2[0], oy = (float)o2[1];
  const int z = p & 3;                       // NP=8 split (2,4): z = p % 4
  const float rx = ref[((size_t)row * 4 + z) * 2 + 0];
  const float ry = ref[((size_t)row * 4 + z) * 2 + 1];
  const int Wl = lvl_w[l], Hl = lvl_h[l], st = lvl_s[l];

  const float px = fmaf(rx, (float)Wl, ox) - 0.5f;
  const float py = fmaf(ry, (float)Hl, oy) - 0.5f;
  const float x0f = floorf(px), y0f = floorf(py);
  const float wx = px - x0f, wy = py - y0f;
  const int x0 = (int)x0f, y0 = (int)y0f;
  const int x1 = x0 + 1,   y1 = y0 + 1;

  // x: one 128B segment based at xb covers slots xb (left) and xb+1 (right)
  const float mx0 = (x0 >= 0 && x0 < Wl) ? 1.f : 0.f;
  const float mx1 = (x1 >= 0 && x1 < Wl) ? 1.f : 0.f;
  const float my0 = (y0 >= 0 && y0 < Hl) ? 1.f : 0.f;
  const float my1 = (y1 >= 0 && y1 < Hl) ? 1.f : 0.f;
  const int xb  = min(max(x0, -1), Wl - 1);          // guard pages cover x=-1/W
  const int cy0 = min(max(y0, 0), Hl - 1);
  const int cy1 = min(max(y1, 0), Hl - 1);

  const int bh   = b * NH + h;
  const int lbase = bh * S_TOTAL + st;
  const float wlc = attnw * (1.f - wx) * mx0;
  const float wrc = attnw * wx * mx1;

  addr_s[2 * t + 0] = (lbase + cy0 * Wl + xb) * 32;
  addr_s[2 * t + 1] = (lbase + cy1 * Wl + xb) * 32;
  wl_s[2 * t + 0] = wlc * (1.f - wy) * my0;
  wr_s[2 * t + 0] = wrc * (1.f - wy) * my0;
  wl_s[2 * t + 1] = wlc * wy * my1;
  wr_s[2 * t + 1] = wrc * wy * my1;
  __syncthreads();

  // ---- phase 2: lane g = (ph, side, chquad) within head group ----
  const int g  = t & 31;
  const int c  = g & 7;           // channel quad: channels 4c..4c+3
  const int sd = (g >> 3) & 1;    // 0 = left corner, 1 = right corner
  const int ph = g >> 4;          // point parity
  const int ldoff = sd * 32 + 4 * c;

  // load everything first (32 independent loads in flight), then fma
  half4v vt[16], vb[16];
  float wt[16], wb[16];
  #pragma unroll
  for (int i = 0; i < 16; ++i) {
    const int idx = ((h << 5) + 2 * i + ph) * 2;
    const int at = addr_s[idx], ab = addr_s[idx + 1];
    wt[i] = sd ? wr_s[idx]     : wl_s[idx];
    wb[i] = sd ? wr_s[idx + 1] : wl_s[idx + 1];
    vt[i] = *(const half4v*)(vproj + at + ldoff);
    vb[i] = *(const half4v*)(vproj + ab + ldoff);
  }

  float a0 = 0.f, a1 = 0.f, a2 = 0.f, a3 = 0.f;
  #pragma unroll
  for (int i = 0; i < 16; ++i) {
    a0 = fmaf(wt[i], (float)vt[i][0], a0); a1 = fmaf(wt[i], (float)vt[i][1], a1);
    a2 = fmaf(wt[i], (float)vt[i][2], a2); a3 = fmaf(wt[i], (float)vt[i][3], a3);
    a0 = fmaf(wb[i], (float)vb[i][0], a0); a1 = fmaf(wb[i], (float)vb[i][1], a1);
    a2 = fmaf(wb[i], (float)vb[i][2], a2); a3 = fmaf(wb[i], (float)vb[i][3], a3);
  }

  // reduce over side (xor 8) and point parity (xor 16)
  a0 += __shfl_xor(a0, 8);  a1 += __shfl_xor(a1, 8);
  a2 += __shfl_xor(a2, 8);  a3 += __shfl_xor(a3, 8);
  a0 += __shfl_xor(a0, 16); a1 += __shfl_xor(a1, 16);
  a2 += __shfl_xor(a2, 16); a3 += __shfl_xor(a3, 16);

  if (g < 8) {    // sd==0 && ph==0: 8 lanes own the 8 channel quads
    float4 o; o.x = a0; o.y = a1; o.z = a2; o.w = a3;
    *(float4*)(out + (size_t)row * 256 + (h << 5) + 4 * c) = o;
  }
}

extern "C" void kernel_launch(void* const* d_in, const int* in_sizes, int n_in,
                              void* d_out, int out_size, void* d_ws, size_t ws_size,
                              hipStream_t stream) {
  const float* query  = (const float*)d_in[0];  // [4,10000,256]
  const float* value  = (const float*)d_in[1];  // [4,19560,256]
  const float* refpts = (const float*)d_in[2];  // [4,10000,4,2]
  const float* w_off  = (const float*)d_in[3];  // [256,512]
  const float* b_off  = (const float*)d_in[4];  // [512]
  const float* w_attn = (const float*)d_in[5];  // [256,256]
  const float* b_attn = (const float*)d_in[6];  // [256]
  const float* w_val  = (const float*)d_in[7];  // [256,256]
  const float* b_val  = (const float*)d_in[8];  // [256]
  float* out = (float*)d_out;

  // workspace layout (16B-multiple segments; 256B guards around vh for the
  // x=-1 / x=W edge reads, whose weights are zero)
  char* p = (char*)d_ws;
  p += 256;                                                         // front guard
  _Float16* vh    = (_Float16*)p;  p += (size_t)VROWS * 256 * 2;    // 40.1 MB
  p += 256;                                                         // back guard
  _Float16* wT768 = (_Float16*)p;  p += (size_t)768 * 256 * 2;      // swizzled
  _Float16* wvaT  = (_Float16*)p;  p += (size_t)256 * 256 * 2;      // swizzled
  _Float16* fused_h = (_Float16*)p; p += (size_t)NROW * 768 * 2;    // 61.4 MB

  // prep: all weight transposes in one launch
  prep_weights<<<1024, 256, 0, stream>>>(w_off, w_attn, w_val, wT768, wvaT);

  // GEMMs: A register-resident, B chunks via LDS.
  // v = value@w_val -> [B,H,S,32] swizzled; fused = query@[w_off|w_attn]
  gemm5<256, 1, true><<<dim3((VROWS + 127) / 128, 1), 256, 0, stream>>>(
      value, wvaT, b_val, b_val, 1 << 30, vh, VROWS);
  gemm5<768, 2, false><<<dim3((NROW + 127) / 128, 2), 256, 0, stream>>>(
      query, wT768, b_off, b_attn, 512, fused_h, NROW);

  // softmax + sample + weighted sum
  msda_sample<<<dim3(NROW), 256, 0, stream>>>(vh, fused_h, refpts, out);
}